// Round 1
// baseline (2006.835 us; speedup 1.0000x reference)
//
#include <hip/hip_runtime.h>
#include <stdint.h>

// GRANMixtureBernoulli: E=4194304 edges, K=20 comps, S=4096 segments.
// v2: counting-sort pipeline. The old role-split LDS-atomic accumulate was stalled on
// LDS atomic RMW serialization (~270 cyc/wave-op implied; VALU 4.7%, HBM 21%, all idle).
// New: hist -> scan -> scatter sorted edge ids -> register run-length accumulate (no LDS atomics).

#define S_SEG 4096
#define K_COMP 20
#define TPE 16          // sorted edges per thread in accum (runs avg ~1024/segment, so ~1 flush/thread)

__device__ __forceinline__ float sp_f(float x) {
    // softplus(x) = max(x,0) + log1p(exp(-|x|)); fast-math fine for scalar tolerance
    return fmaxf(x, 0.f) + __logf(1.f + __expf(-fabsf(x)));
}

__device__ __forceinline__ void gatomic_add_f(float* p, float v) {
    __hip_atomic_fetch_add(p, v, __ATOMIC_RELAXED, __HIP_MEMORY_SCOPE_AGENT);
}

// ---------------- hist: per-segment counts (LDS hist -> global) ----------------
__global__ __launch_bounds__(256) void pack_count_kernel(
    const int* __restrict__ sidx, const float* __restrict__ label,
    unsigned short* __restrict__ packed, unsigned int* __restrict__ g_cnt,
    int E4, int doPack)
{
    __shared__ unsigned int hist[S_SEG];
    for (int i = threadIdx.x; i < S_SEG; i += 256) hist[i] = 0u;
    __syncthreads();

    const int4* s4 = (const int4*)sidx;
    int gt = blockIdx.x * 256 + threadIdx.x;
    int stride = gridDim.x * 256;
    for (int i = gt; i < E4; i += stride) {
        int4 sv = s4[i];
        atomicAdd(&hist[sv.x & 4095], 1u);
        atomicAdd(&hist[sv.y & 4095], 1u);
        atomicAdd(&hist[sv.z & 4095], 1u);
        atomicAdd(&hist[sv.w & 4095], 1u);
    }
    __syncthreads();
    for (int i = threadIdx.x; i < S_SEG; i += 256) {
        unsigned int c = hist[i];
        if (c) atomicAdd(&g_cnt[i], c);
    }
    (void)label; (void)packed; (void)doPack;
}

// ---------------- scan: exclusive prefix over 4096 counts, one block ----------------
__global__ __launch_bounds__(1024) void scan_kernel(
    const unsigned int* __restrict__ g_cnt,
    unsigned int* __restrict__ g_pref, unsigned int* __restrict__ g_cur)
{
    __shared__ unsigned int ts[1024];
    const int tid = threadIdx.x;

    uint4 c = ((const uint4*)g_cnt)[tid];            // 4 counts per thread
    unsigned s0 = c.x;
    unsigned s1 = s0 + c.y;
    unsigned s2 = s1 + c.z;
    unsigned s3 = s2 + c.w;
    ts[tid] = s3;
    __syncthreads();

    // Hillis-Steele inclusive scan over 1024 thread sums
    for (int off = 1; off < 1024; off <<= 1) {
        unsigned v = 0;
        if (tid >= off) v = ts[tid - off];
        __syncthreads();
        ts[tid] += v;
        __syncthreads();
    }

    unsigned base = ts[tid] - s3;                    // exclusive prefix for this thread's 4
    uint4 p;
    p.x = base;
    p.y = base + s0;
    p.z = base + s1;
    p.w = base + s2;
    ((uint4*)g_pref)[tid] = p;
    ((uint4*)g_cur)[tid]  = p;                       // live cursors for scatter
    if (tid == 1023) g_pref[S_SEG] = ts[1023];       // total = E
}

// ---------------- scatter: edge ids (| label bit) into segment-sorted order ----------------
__global__ __launch_bounds__(256) void scatter_kernel(
    const int* __restrict__ sidx, const float* __restrict__ label,
    unsigned int* __restrict__ g_cur, unsigned int* __restrict__ sorted, int E4)
{
    const int4*   s4 = (const int4*)sidx;
    const float4* l4 = (const float4*)label;
    int i = blockIdx.x * 256 + threadIdx.x;
    int stride = gridDim.x * 256;
    for (; i < E4; i += stride) {
        int4   sv = s4[i];
        float4 lv = l4[i];
        unsigned e = (unsigned)i * 4u;
        unsigned p;
        p = atomicAdd(&g_cur[sv.x & 4095], 1u); sorted[p] = (e    ) | (lv.x != 0.f ? 0x80000000u : 0u);
        p = atomicAdd(&g_cur[sv.y & 4095], 1u); sorted[p] = (e + 1) | (lv.y != 0.f ? 0x80000000u : 0u);
        p = atomicAdd(&g_cur[sv.z & 4095], 1u); sorted[p] = (e + 2) | (lv.z != 0.f ? 0x80000000u : 0u);
        p = atomicAdd(&g_cur[sv.w & 4095], 1u); sorted[p] = (e + 3) | (lv.w != 0.f ? 0x80000000u : 0u);
    }
}

// ---------------- accum: register run-length accumulation over sorted edges ----------------
__device__ __forceinline__ void flush_acc(
    float* __restrict__ g_adj, float* __restrict__ g_alp,
    int s, const float4 (&aj)[5], const float4 (&al)[5])
{
    float* pa = g_adj + (size_t)s * K_COMP;
    float* pl = g_alp + (size_t)s * K_COMP;
    #pragma unroll
    for (int k = 0; k < 5; ++k) {
        gatomic_add_f(pa + k*4 + 0, aj[k].x);
        gatomic_add_f(pa + k*4 + 1, aj[k].y);
        gatomic_add_f(pa + k*4 + 2, aj[k].z);
        gatomic_add_f(pa + k*4 + 3, aj[k].w);
        gatomic_add_f(pl + k*4 + 0, al[k].x);
        gatomic_add_f(pl + k*4 + 1, al[k].y);
        gatomic_add_f(pl + k*4 + 2, al[k].z);
        gatomic_add_f(pl + k*4 + 3, al[k].w);
    }
}

__global__ __launch_bounds__(256) void accum_kernel(
    const float* __restrict__ theta, const float* __restrict__ alpha,
    const unsigned int* __restrict__ sorted, const unsigned int* __restrict__ g_pref,
    float* __restrict__ g_adj, float* __restrict__ g_alp, int E)
{
    __shared__ unsigned int pref[S_SEG + 1];
    for (int i = threadIdx.x; i < S_SEG + 1; i += 256) pref[i] = g_pref[i];
    __syncthreads();

    int p0 = (blockIdx.x * 256 + threadIdx.x) * TPE;
    if (p0 >= E) return;
    int p1 = p0 + TPE; if (p1 > E) p1 = E;

    // largest s with pref[s] <= p0  (pref[0]=0, pref[4096]=E keep the invariant)
    int lo = 0, hi = S_SEG;
    while (hi - lo > 1) {
        int mid = (lo + hi) >> 1;
        if (pref[mid] <= (unsigned)p0) lo = mid; else hi = mid;
    }
    int s = lo;
    unsigned nxt = pref[s + 1];

    float4 aj[5], al[5];
    #pragma unroll
    for (int k = 0; k < 5; ++k) { aj[k] = make_float4(0,0,0,0); al[k] = make_float4(0,0,0,0); }

    const float4* t4 = (const float4*)theta;
    const float4* a4 = (const float4*)alpha;

    for (int p = p0; p < p1; ++p) {
        if ((unsigned)p == nxt) {                      // segment boundary: flush & advance
            flush_acc(g_adj, g_alp, s, aj, al);
            do { ++s; } while (pref[s + 1] <= (unsigned)p);   // skip empty segments
            nxt = pref[s + 1];
            #pragma unroll
            for (int k = 0; k < 5; ++k) { aj[k] = make_float4(0,0,0,0); al[k] = make_float4(0,0,0,0); }
        }
        unsigned pay = sorted[p];
        unsigned e   = pay & 0x7fffffffu;
        float    lab = (pay & 0x80000000u) ? 1.f : 0.f;
        size_t   b   = (size_t)e * 5;
        #pragma unroll
        for (int k = 0; k < 5; ++k) {
            float4 tv = t4[b + k];
            float4 av = a4[b + k];
            aj[k].x += sp_f(tv.x) - tv.x * lab;
            aj[k].y += sp_f(tv.y) - tv.y * lab;
            aj[k].z += sp_f(tv.z) - tv.z * lab;
            aj[k].w += sp_f(tv.w) - tv.w * lab;
            al[k].x += av.x;
            al[k].y += av.y;
            al[k].z += av.z;
            al[k].w += av.w;
        }
    }
    flush_acc(g_adj, g_alp, s, aj, al);
}

// ---------------- fallback accumulate (previous version, unpacked path) ----------------
template<bool PACKED>
__global__ __launch_bounds__(256) void seg_accum_kernel(
    const float* __restrict__ theta, const float* __restrict__ alpha,
    const unsigned short* __restrict__ packed,
    const int* __restrict__ sidx, const float* __restrict__ label,
    float* __restrict__ g_adj, float* __restrict__ g_alp,
    int ntiles)
{
    __shared__ float tab[4 * S_SEG];
    for (int i = threadIdx.x; i < 4 * S_SEG; i += 256) tab[i] = 0.f;
    __syncthreads();

    const int  role  = blockIdx.x;
    const bool isAdj = role < 5;
    const int  c4    = isAdj ? role : role - 5;
    const float4* src4 = (const float4*)(isAdj ? theta : alpha);
    const int nY = gridDim.y;

    for (int t = blockIdx.y; t < ntiles; t += nY) {
        int eA = t * 256 + threadIdx.x;
        float4 vA = src4[(size_t)eA * 5 + c4];
        int sA = sidx[eA] & 4095;
        float labA = label[eA];
        if (isAdj) {
            vA.x = sp_f(vA.x) - vA.x * labA;
            vA.y = sp_f(vA.y) - vA.y * labA;
            vA.z = sp_f(vA.z) - vA.z * labA;
            vA.w = sp_f(vA.w) - vA.w * labA;
        }
        atomicAdd(&tab[            sA], vA.x);
        atomicAdd(&tab[1 * S_SEG + sA], vA.y);
        atomicAdd(&tab[2 * S_SEG + sA], vA.z);
        atomicAdd(&tab[3 * S_SEG + sA], vA.w);
    }
    __syncthreads();

    float* g = isAdj ? g_adj : g_alp;
    const int k0 = c4 * 4;
    for (int j = threadIdx.x; j < 4 * S_SEG; j += 256) {
        int kk = j >> 12;
        int ss = j & 4095;
        gatomic_add_f(&g[ss * K_COMP + k0 + kk], tab[j]);
    }
    (void)packed;
}

// ---------------- finalize: one block ----------------
__global__ __launch_bounds__(256) void finalize_kernel(
    const float* __restrict__ g_adj, const float* __restrict__ g_alp,
    const unsigned int* __restrict__ g_cnt, float* __restrict__ out, float Ef)
{
    float local = 0.f;
    for (int s = threadIdx.x; s < S_SEG; s += 256) {
        float c = (float)g_cnt[s];
        if (c < 1.f) c = 1.f;
        float inv = 1.f / c;

        float a[K_COMP];
        float am = -1e30f;
        #pragma unroll
        for (int k = 0; k < K_COMP; ++k) {
            a[k] = g_alp[s * K_COMP + k] * inv;
            am = fmaxf(am, a[k]);
        }
        float den = 0.f;
        #pragma unroll
        for (int k = 0; k < K_COMP; ++k) den += __expf(a[k] - am);
        float lse = am + __logf(den);

        float t[K_COMP];
        float tm = -1e30f;
        #pragma unroll
        for (int k = 0; k < K_COMP; ++k) {
            t[k] = (a[k] - lse) - g_adj[s * K_COMP + k];
            tm = fmaxf(tm, t[k]);
        }
        float d2 = 0.f;
        #pragma unroll
        for (int k = 0; k < K_COMP; ++k) d2 += __expf(t[k] - tm);
        local += tm + __logf(d2);
    }

    __shared__ float red[256];
    red[threadIdx.x] = local;
    __syncthreads();
    for (int o = 128; o > 0; o >>= 1) {
        if (threadIdx.x < o) red[threadIdx.x] += red[threadIdx.x + o];
        __syncthreads();
    }
    if (threadIdx.x == 0) out[0] = -red[0] / Ef;
}

extern "C" void kernel_launch(void* const* d_in, const int* in_sizes, int n_in,
                              void* d_out, int out_size, void* d_ws, size_t ws_size,
                              hipStream_t stream)
{
    const float* label = (const float*)d_in[0];
    const float* theta = (const float*)d_in[1];
    const float* alpha = (const float*)d_in[2];
    const int*   sidx  = (const int*)d_in[3];
    const int E = in_sizes[0];

    // ws layout (256B-aligned chunks):
    // [g_adj 4096*20 f32][g_alp 4096*20 f32][g_cnt 4096 u32][g_cur 4096 u32][g_pref 4160 u32][sorted E u32]
    float* g_adj = (float*)d_ws;
    float* g_alp = g_adj + S_SEG * K_COMP;
    unsigned int* g_cnt  = (unsigned int*)(g_alp + S_SEG * K_COMP);
    unsigned int* g_cur  = g_cnt + S_SEG;
    unsigned int* g_pref = g_cur + S_SEG;
    unsigned int* sorted = g_pref + 4160;                 // 4097 used, padded for alignment
    const size_t tablesBytes = (size_t)S_SEG * K_COMP * 4 * 2 + (size_t)S_SEG * 4;  // 671744
    const size_t need = tablesBytes + (size_t)S_SEG * 4 + 4160 * 4 + (size_t)E * 4;

    hipMemsetAsync(d_ws, 0, tablesBytes, stream);        // zero adj/alp tables + counts

    pack_count_kernel<<<256, 256, 0, stream>>>(sidx, label, nullptr, g_cnt, E / 4, 0);

    if (ws_size >= need && (E % 4) == 0) {
        scan_kernel<<<1, 1024, 0, stream>>>(g_cnt, g_pref, g_cur);
        scatter_kernel<<<1024, 256, 0, stream>>>(sidx, label, g_cur, sorted, E / 4);
        int ablocks = (E / TPE + 255) / 256;             // 1024 for E=4.19M
        accum_kernel<<<ablocks, 256, 0, stream>>>(theta, alpha, sorted, g_pref,
                                                  g_adj, g_alp, E);
    } else {
        // fallback: previous role-split LDS-atomic path
        seg_accum_kernel<false><<<dim3(10, 96), 256, 0, stream>>>(theta, alpha, nullptr,
                                                                  sidx, label, g_adj, g_alp,
                                                                  E / 256);
    }

    finalize_kernel<<<1, 256, 0, stream>>>(g_adj, g_alp, g_cnt, (float*)d_out, (float)E);
}

// Round 2
// 1660.869 us; speedup vs baseline: 1.2083x; 1.2083x over previous
//
#include <hip/hip_runtime.h>
#include <stdint.h>

// GRANMixtureBernoulli: E=4194304 edges, K=20 comps, S=4096 segments.
// v3: all-streaming transpose pipeline. v1 (strided role reads) and v2 (sorted random
// gather) both plateaued at ~1.4-1.7 TB/s effective HBM with all pipes idle ->
// pattern-limited HBM. v3 makes every stream contiguous:
//   T1: stream theta/label/sidx -> softplus -> write k-chunk planes adjT[c][e] (coalesced)
//       + packed u16 seg ids + per-block hist partials (no atomics)
//   R:  per-k-chunk role blocks read plane coalesced, LDS table accumulate (4 ds_add/edge),
//       flush per-block partials non-atomically
//   reduce: sum partials -> g_adj / g_alp (+ counts)
//   T2/R/reduce again for alpha, reusing the same plane buffer (ws ~395 MB)
// Fallback to the round-0 pipeline when ws is too small.

#define S_SEG 4096
#define K_COMP 20
#define THB 1024      // T1 grid blocks (fixed: part_hist rows)
#define RY 102        // R grid.y (role blocks per k-chunk)
#define RT 512        // R block threads

__device__ __forceinline__ float sp_f(float x) {
    // softplus(x) = max(x,0) + log1p(exp(-|x|))
    return fmaxf(x, 0.f) + __logf(1.f + __expf(-fabsf(x)));
}

__device__ __forceinline__ void gatomic_add_f(float* p, float v) {
    __hip_atomic_fetch_add(p, v, __ATOMIC_RELAXED, __HIP_MEMORY_SCOPE_AGENT);
}

// ---------------- T1: theta stage — softplus + transpose + pack + hist partials ----------------
__global__ __launch_bounds__(256) void t1_kernel(
    const float* __restrict__ theta, const float* __restrict__ label,
    const int* __restrict__ sidx,
    float* __restrict__ adjT, unsigned short* __restrict__ packed,
    unsigned int* __restrict__ part_hist, int E)
{
    __shared__ unsigned int hist[S_SEG];
    for (int i = threadIdx.x; i < S_SEG; i += 256) hist[i] = 0u;
    __syncthreads();

    const float4* t4 = (const float4*)theta;
    float4*       o4 = (float4*)adjT;

    int gt = blockIdx.x * 256 + threadIdx.x;
    int stride = gridDim.x * 256;
    for (int e = gt; e < E; e += stride) {
        int s = sidx[e] & 4095;
        float lab = label[e];
        atomicAdd(&hist[s], 1u);
        packed[e] = (unsigned short)s;
        size_t b = (size_t)e * 5;
        #pragma unroll
        for (int c = 0; c < 5; ++c) {
            float4 v = t4[b + c];
            v.x = sp_f(v.x) - v.x * lab;
            v.y = sp_f(v.y) - v.y * lab;
            v.z = sp_f(v.z) - v.z * lab;
            v.w = sp_f(v.w) - v.w * lab;
            o4[(size_t)c * E + e] = v;      // coalesced per-plane store
        }
    }
    __syncthreads();
    unsigned int* ph = part_hist + (size_t)blockIdx.x * S_SEG;
    for (int i = threadIdx.x; i < S_SEG; i += 256) ph[i] = hist[i];
}

// ---------------- T2: alpha stage — pure transpose ----------------
__global__ __launch_bounds__(256) void t2_kernel(
    const float* __restrict__ alpha, float* __restrict__ alpT, int E)
{
    const float4* a4 = (const float4*)alpha;
    float4*       o4 = (float4*)alpT;
    int gt = blockIdx.x * 256 + threadIdx.x;
    int stride = gridDim.x * 256;
    for (int e = gt; e < E; e += stride) {
        size_t b = (size_t)e * 5;
        #pragma unroll
        for (int c = 0; c < 5; ++c) o4[(size_t)c * E + e] = a4[b + c];
    }
}

// ---------------- R: per-k-chunk coalesced accumulate into LDS table ----------------
__global__ __launch_bounds__(RT) void r_kernel(
    const float* __restrict__ planes, const unsigned short* __restrict__ packed,
    float* __restrict__ partial, int E, int ntiles)
{
    __shared__ float tab[4 * S_SEG];                 // 64 KB, [kk][s]
    for (int i = threadIdx.x; i < 4 * S_SEG; i += RT) tab[i] = 0.f;
    __syncthreads();

    const int c4 = blockIdx.x;                       // 0..4
    const float4* src = ((const float4*)planes) + (size_t)c4 * E;
    const int tid = threadIdx.x;

    for (int t = blockIdx.y; t < ntiles; t += 2 * RY) {
        const int tB = t + RY;
        const bool hasB = (tB < ntiles);

        int eA = t * RT + tid;
        bool okA = (eA < E);
        float4 vA; int sA = 0;
        if (okA) { vA = src[eA]; sA = packed[eA]; }

        int eB = hasB ? tB * RT + tid : 0;
        bool okB = hasB && (eB < E);
        float4 vB; int sB = 0;
        if (okB) { vB = src[eB]; sB = packed[eB]; }

        if (okA) {
            atomicAdd(&tab[             sA], vA.x);
            atomicAdd(&tab[1 * S_SEG + sA], vA.y);
            atomicAdd(&tab[2 * S_SEG + sA], vA.z);
            atomicAdd(&tab[3 * S_SEG + sA], vA.w);
        }
        if (okB) {
            atomicAdd(&tab[             sB], vB.x);
            atomicAdd(&tab[1 * S_SEG + sB], vB.y);
            atomicAdd(&tab[2 * S_SEG + sB], vB.z);
            atomicAdd(&tab[3 * S_SEG + sB], vB.w);
        }
    }
    __syncthreads();

    // non-atomic partial flush, coalesced
    float* p = partial + ((size_t)c4 * RY + blockIdx.y) * (4 * S_SEG);
    for (int j = threadIdx.x; j < 4 * S_SEG; j += RT) p[j] = tab[j];
}

// ---------------- reduce: sum R partials -> table; optionally hist partials -> counts ----------------
__global__ __launch_bounds__(256) void reduce_kernel(
    const float* __restrict__ partial, const unsigned int* __restrict__ part_hist,
    float* __restrict__ g_out, unsigned int* __restrict__ g_cnt, int doCnt)
{
    int idx = blockIdx.x * 256 + threadIdx.x;        // 0 .. 5*4*4096-1
    if (idx < 5 * 4 * S_SEG) {
        int s  = idx & 4095;
        int kk = (idx >> 12) & 3;
        int c4 = idx >> 14;
        float acc = 0.f;
        const float* p = partial + (size_t)c4 * RY * (4 * S_SEG) + kk * S_SEG + s;
        for (int y = 0; y < RY; ++y) acc += p[(size_t)y * (4 * S_SEG)];
        g_out[s * K_COMP + c4 * 4 + kk] = acc;
    }
    if (doCnt && idx < S_SEG) {
        unsigned int c = 0;
        for (int y = 0; y < THB; ++y) c += part_hist[(size_t)y * S_SEG + idx];
        g_cnt[idx] = c;
    }
}

// ---------------- fallback (round-0 pipeline) ----------------
__global__ __launch_bounds__(256) void pack_count_kernel(
    const int* __restrict__ sidx, unsigned int* __restrict__ g_cnt, int E4)
{
    __shared__ unsigned int hist[S_SEG];
    for (int i = threadIdx.x; i < S_SEG; i += 256) hist[i] = 0u;
    __syncthreads();
    const int4* s4 = (const int4*)sidx;
    int gt = blockIdx.x * 256 + threadIdx.x;
    int stride = gridDim.x * 256;
    for (int i = gt; i < E4; i += stride) {
        int4 sv = s4[i];
        atomicAdd(&hist[sv.x & 4095], 1u);
        atomicAdd(&hist[sv.y & 4095], 1u);
        atomicAdd(&hist[sv.z & 4095], 1u);
        atomicAdd(&hist[sv.w & 4095], 1u);
    }
    __syncthreads();
    for (int i = threadIdx.x; i < S_SEG; i += 256) {
        unsigned int c = hist[i];
        if (c) atomicAdd(&g_cnt[i], c);
    }
}

__global__ __launch_bounds__(256) void seg_accum_kernel(
    const float* __restrict__ theta, const float* __restrict__ alpha,
    const int* __restrict__ sidx, const float* __restrict__ label,
    float* __restrict__ g_adj, float* __restrict__ g_alp, int ntiles)
{
    __shared__ float tab[4 * S_SEG];
    for (int i = threadIdx.x; i < 4 * S_SEG; i += 256) tab[i] = 0.f;
    __syncthreads();

    const int  role  = blockIdx.x;
    const bool isAdj = role < 5;
    const int  c4    = isAdj ? role : role - 5;
    const float4* src4 = (const float4*)(isAdj ? theta : alpha);
    const int nY = gridDim.y;

    for (int t = blockIdx.y; t < ntiles; t += nY) {
        int eA = t * 256 + threadIdx.x;
        float4 vA = src4[(size_t)eA * 5 + c4];
        int sA = sidx[eA] & 4095;
        float labA = label[eA];
        if (isAdj) {
            vA.x = sp_f(vA.x) - vA.x * labA;
            vA.y = sp_f(vA.y) - vA.y * labA;
            vA.z = sp_f(vA.z) - vA.z * labA;
            vA.w = sp_f(vA.w) - vA.w * labA;
        }
        atomicAdd(&tab[             sA], vA.x);
        atomicAdd(&tab[1 * S_SEG + sA], vA.y);
        atomicAdd(&tab[2 * S_SEG + sA], vA.z);
        atomicAdd(&tab[3 * S_SEG + sA], vA.w);
    }
    __syncthreads();

    float* g = isAdj ? g_adj : g_alp;
    const int k0 = c4 * 4;
    for (int j = threadIdx.x; j < 4 * S_SEG; j += 256) {
        int kk = j >> 12;
        int ss = j & 4095;
        gatomic_add_f(&g[ss * K_COMP + k0 + kk], tab[j]);
    }
}

// ---------------- finalize: one block ----------------
__global__ __launch_bounds__(256) void finalize_kernel(
    const float* __restrict__ g_adj, const float* __restrict__ g_alp,
    const unsigned int* __restrict__ g_cnt, float* __restrict__ out, float Ef)
{
    float local = 0.f;
    for (int s = threadIdx.x; s < S_SEG; s += 256) {
        float c = (float)g_cnt[s];
        if (c < 1.f) c = 1.f;
        float inv = 1.f / c;

        float a[K_COMP];
        float am = -1e30f;
        #pragma unroll
        for (int k = 0; k < K_COMP; ++k) {
            a[k] = g_alp[s * K_COMP + k] * inv;
            am = fmaxf(am, a[k]);
        }
        float den = 0.f;
        #pragma unroll
        for (int k = 0; k < K_COMP; ++k) den += __expf(a[k] - am);
        float lse = am + __logf(den);

        float t[K_COMP];
        float tm = -1e30f;
        #pragma unroll
        for (int k = 0; k < K_COMP; ++k) {
            t[k] = (a[k] - lse) - g_adj[s * K_COMP + k];
            tm = fmaxf(tm, t[k]);
        }
        float d2 = 0.f;
        #pragma unroll
        for (int k = 0; k < K_COMP; ++k) d2 += __expf(t[k] - tm);
        local += tm + __logf(d2);
    }

    __shared__ float red[256];
    red[threadIdx.x] = local;
    __syncthreads();
    for (int o = 128; o > 0; o >>= 1) {
        if (threadIdx.x < o) red[threadIdx.x] += red[threadIdx.x + o];
        __syncthreads();
    }
    if (threadIdx.x == 0) out[0] = -red[0] / Ef;
}

extern "C" void kernel_launch(void* const* d_in, const int* in_sizes, int n_in,
                              void* d_out, int out_size, void* d_ws, size_t ws_size,
                              hipStream_t stream)
{
    const float* label = (const float*)d_in[0];
    const float* theta = (const float*)d_in[1];
    const float* alpha = (const float*)d_in[2];
    const int*   sidx  = (const int*)d_in[3];
    const int E = in_sizes[0];

    // ws layout:
    // [planeBuf E*20 f32][partial 5*RY*4*4096 f32][part_hist THB*4096 u32]
    // [packed E u16][g_adj 4096*20 f32][g_alp 4096*20 f32][g_cnt 4096 u32]
    const size_t planeElems   = (size_t)E * K_COMP;
    const size_t partialElems = (size_t)5 * RY * 4 * S_SEG;
    const size_t phElems      = (size_t)THB * S_SEG;

    float*          planeBuf  = (float*)d_ws;
    float*          partial   = planeBuf + planeElems;
    unsigned int*   part_hist = (unsigned int*)(partial + partialElems);
    unsigned short* packed    = (unsigned short*)(part_hist + phElems);
    float*          g_adj     = (float*)((char*)packed + (((size_t)E * 2 + 255) & ~(size_t)255));
    float*          g_alp     = g_adj + S_SEG * K_COMP;
    unsigned int*   g_cnt     = (unsigned int*)(g_alp + S_SEG * K_COMP);

    const size_t need = (size_t)((char*)(g_cnt + S_SEG) - (char*)d_ws);

    if (ws_size >= need) {
        const int ntiles = (E + RT - 1) / RT;
        dim3 rgrid(5, RY);

        t1_kernel<<<THB, 256, 0, stream>>>(theta, label, sidx, planeBuf, packed, part_hist, E);
        r_kernel<<<rgrid, RT, 0, stream>>>(planeBuf, packed, partial, E, ntiles);
        reduce_kernel<<<320, 256, 0, stream>>>(partial, part_hist, g_adj, g_cnt, 1);

        t2_kernel<<<2048, 256, 0, stream>>>(alpha, planeBuf, E);
        r_kernel<<<rgrid, RT, 0, stream>>>(planeBuf, packed, partial, E, ntiles);
        reduce_kernel<<<320, 256, 0, stream>>>(partial, part_hist, g_alp, g_cnt, 0);

        finalize_kernel<<<1, 256, 0, stream>>>(g_adj, g_alp, g_cnt, (float*)d_out, (float)E);
    } else {
        // fallback: round-0 pipeline in a small ws
        float* f_adj = (float*)d_ws;
        float* f_alp = f_adj + S_SEG * K_COMP;
        unsigned int* f_cnt = (unsigned int*)(f_alp + S_SEG * K_COMP);
        const size_t tablesBytes = (size_t)S_SEG * K_COMP * 4 * 2 + (size_t)S_SEG * 4;

        hipMemsetAsync(d_ws, 0, tablesBytes, stream);
        pack_count_kernel<<<256, 256, 0, stream>>>(sidx, f_cnt, E / 4);
        seg_accum_kernel<<<dim3(10, 96), 256, 0, stream>>>(theta, alpha, sidx, label,
                                                           f_adj, f_alp, E / 256);
        finalize_kernel<<<1, 256, 0, stream>>>(f_adj, f_alp, f_cnt, (float*)d_out, (float)E);
    }
}